// Round 3
// baseline (271.365 us; speedup 1.0000x reference)
//
#include <hip/hip_runtime.h>

// Dtype-agnostic ingest: a detector kernel decides whether d_in buffers are
// f32 or bf16; compute is bf16 MFMA; final output written as FLOAT32
// (reference's output dtype per the harness contract).

typedef __bf16 bf16x8 __attribute__((ext_vector_type(8)));
typedef float f32x4 __attribute__((ext_vector_type(4)));

#define DEV __device__ __forceinline__

DEV unsigned short f2bf(float f) {
  union { float f; unsigned u; } x; x.f = f;
  unsigned r = x.u + 0x7FFFu + ((x.u >> 16) & 1u);  // RNE
  return (unsigned short)(r >> 16);
}
DEV float bf2f(unsigned short h) {
  union { unsigned u; float f; } x; x.u = ((unsigned)h) << 16;
  return x.f;
}

// ---- dtype detector: f32 buffers read as bf16 have mantissa-noise shorts
// with uniform exponent bytes (~25% >= 0xC0); genuine N(0,1) bf16 has none.
__global__ void detect_dtype_k(const unsigned short* __restrict__ x,
                               int* __restrict__ flag) {
  __shared__ int cnt;
  if (threadIdx.x == 0) cnt = 0;
  __syncthreads();
  int c = 0;
  for (int i = threadIdx.x; i < 8192; i += 256) {
    unsigned e = (x[i] >> 7) & 0xFFu;
    c += (e >= 0xC0u) ? 1 : 0;
  }
  atomicAdd(&cnt, c);
  __syncthreads();
  if (threadIdx.x == 0) *flag = (cnt > 64) ? 1 : 0;
}

// ---- convert (or copy) a flat tensor to bf16
__global__ void cvt_k(const void* __restrict__ src, unsigned short* __restrict__ dst,
                      int n, const int* __restrict__ flag) {
  const int f = *flag;
  const float* sf = (const float*)src;
  const unsigned short* su = (const unsigned short*)src;
  for (int i = blockIdx.x * 256 + threadIdx.x; i < n; i += gridDim.x * 256)
    dst[i] = f ? f2bf(sf[i]) : su[i];
}

// ---- transpose + convert: dst[C][R] = src[R][C]
__global__ void transpose_cvt_k(const void* __restrict__ src,
                                unsigned short* __restrict__ dst, int R, int C,
                                const int* __restrict__ flag) {
  __shared__ unsigned short tile[32][33];
  const int f = *flag;
  const float* sf = (const float*)src;
  const unsigned short* su = (const unsigned short*)src;
  int c0 = blockIdx.x * 32, r0 = blockIdx.y * 32;
  int tx = threadIdx.x, ty = threadIdx.y;  // block (32, 8)
  #pragma unroll
  for (int i = 0; i < 4; ++i) {
    size_t idx = (size_t)(r0 + ty + i * 8) * C + c0 + tx;
    tile[ty + i * 8][tx] = f ? f2bf(sf[idx]) : su[idx];
  }
  __syncthreads();
  #pragma unroll
  for (int i = 0; i < 4; ++i)
    dst[(size_t)(c0 + ty + i * 8) * R + r0 + tx] = tile[tx][ty + i * 8];
}

// ---------------- GEMM C = A @ Bt^T  (A[M][K], Bt[N][K], both bf16) --------
// 128x128 tile, BK=32, 4 waves each 64x64 (4x4 of 16x16x32 MFMA).
// mode 1: split cols into q/k/v (bf16, [b,h,n,d]). mode 2: +bias, f32 row-major.
__global__ __launch_bounds__(256)
void gemm_bt(const unsigned short* __restrict__ A,
             const unsigned short* __restrict__ Bt,
             int M, int N, int K, int mode,
             const unsigned short* __restrict__ bias,
             unsigned short* __restrict__ o0,
             unsigned short* __restrict__ o1,
             unsigned short* __restrict__ o2,
             float* __restrict__ fo) {
  __shared__ __align__(16) unsigned short As[128][40];  // +8 pad, rows 80B
  __shared__ __align__(16) unsigned short Bs[128][40];
  const int tid  = threadIdx.x;
  const int lane = tid & 63, wave = tid >> 6;
  const int q15  = lane & 15, quad = lane >> 4;
  const int wr = wave >> 1, wc = wave & 1;
  const int m0 = blockIdx.y * 128, n0 = blockIdx.x * 128;

  f32x4 acc[4][4] = {};

  for (int k0 = 0; k0 < K; k0 += 32) {
    __syncthreads();
    #pragma unroll
    for (int cc = 0; cc < 2; ++cc) {
      int ci = tid + cc * 256;          // 512 chunks of 8 bf16
      int row = ci >> 2, kc = (ci & 3) * 8;
      *(uint4*)&As[row][kc] = *(const uint4*)&A[(size_t)(m0 + row) * K + k0 + kc];
      *(uint4*)&Bs[row][kc] = *(const uint4*)&Bt[(size_t)(n0 + row) * K + k0 + kc];
    }
    __syncthreads();
    bf16x8 af[4], bfr[4];
    #pragma unroll
    for (int i = 0; i < 4; ++i) {
      af[i]  = *(const bf16x8*)&As[wr * 64 + i * 16 + q15][quad * 8];
      bfr[i] = *(const bf16x8*)&Bs[wc * 64 + i * 16 + q15][quad * 8];
    }
    #pragma unroll
    for (int i = 0; i < 4; ++i)
      #pragma unroll
      for (int j = 0; j < 4; ++j)
        acc[i][j] = __builtin_amdgcn_mfma_f32_16x16x32_bf16(af[i], bfr[j], acc[i][j], 0, 0, 0);
  }

  // epilogue — C/D layout: col = lane&15, row = quad*4 + r  (m89/m91 verified)
  #pragma unroll
  for (int i = 0; i < 4; ++i)
    #pragma unroll
    for (int j = 0; j < 4; ++j)
      #pragma unroll
      for (int r = 0; r < 4; ++r) {
        int row = m0 + wr * 64 + i * 16 + quad * 4 + r;
        int col = n0 + wc * 64 + j * 16 + q15;
        float v = acc[i][j][r];
        if (mode == 2) {
          fo[(size_t)row * N + col] = v + bf2f(bias[col]);   // f32 output
        } else {
          int b = row >> 10, nn = row & 1023;
          unsigned short* dst; int c = col;
          if (col < 1024)      { dst = o0; }
          else if (col < 2048) { dst = o1; c = col - 1024; }
          else                 { dst = o2; c = col - 2048; }
          int h = c >> 6, dd = c & 63;
          dst[((size_t)(b * 16 + h) * 1024 + nn) * 64 + dd] = f2bf(v);
        }
      }
}

// ---------------- flash attention with relative-position band ---------------
// grid (16 i-tiles, 32 bh); 4 waves x 16 Q-rows each; j-tiles of 64.
// S = scale*(Q K^T + T-gather), T[dl][u] = q_dl . rel_emb[clamp(tbase+u)]
__global__ __launch_bounds__(256)
void flash_attn(const unsigned short* __restrict__ q_ws,
                const unsigned short* __restrict__ k_ws,
                const unsigned short* __restrict__ v_ws,
                const unsigned short* __restrict__ rel,   // [1025][64]
                unsigned short* __restrict__ ao) {        // [2048][1024]
  __shared__ __align__(16) unsigned short vt[64][72];        // V^T tile (d-major)
  __shared__ __align__(16) float T_lds[4][16][80];           // per-wave pos band
  __shared__ __align__(16) unsigned short P_lds[4][16][72];  // per-wave P staging

  const int tid  = threadIdx.x;
  const int lane = tid & 63, w = tid >> 6;
  const int q15  = lane & 15, quad = lane >> 4;
  const int bh = blockIdx.y;
  const int i0 = blockIdx.x * 64;
  const int ib = i0 + w * 16;  // this wave's first Q row

  const unsigned short* qp = q_ws + (size_t)bh * 1024 * 64;
  const unsigned short* kp = k_ws + (size_t)bh * 1024 * 64;
  const unsigned short* vp = v_ws + (size_t)bh * 1024 * 64;

  // Q strip in A-fragment layout: A[m=lane&15][k=quad*8+j], 2 k-steps of 32
  bf16x8 aq[2];
  #pragma unroll
  for (int ks = 0; ks < 2; ++ks)
    aq[ks] = *(const bf16x8*)&qp[(size_t)(ib + q15) * 64 + ks * 32 + quad * 8];

  f32x4 o[4] = {};
  float m_i[4], l_i[4];
  #pragma unroll
  for (int r = 0; r < 4; ++r) { m_i[r] = -60000.f; l_i[r] = 0.f; }

  for (int j0 = 0; j0 < 1024; j0 += 64) {
    __syncthreads();  // protect vt from previous iteration's readers
    // stage V^T tile (transpose on the fly)
    #pragma unroll
    for (int cc = 0; cc < 2; ++cc) {
      int ci = tid + cc * 256;
      int jr = ci >> 3, d8 = (ci & 7) * 8;
      union { uint4 v; unsigned short us[8]; } t;
      t.v = *(const uint4*)&vp[(size_t)(j0 + jr) * 64 + d8];
      #pragma unroll
      for (int e = 0; e < 8; ++e) vt[d8 + e][jr] = t.us[e];
    }
    // Q K^T (B-frags straight from global k rows — L2-resident)
    f32x4 accS[4] = {};
    #pragma unroll
    for (int ks = 0; ks < 2; ++ks)
      #pragma unroll
      for (int cb = 0; cb < 4; ++cb) {
        bf16x8 bk = *(const bf16x8*)&kp[(size_t)(j0 + cb * 16 + q15) * 64 + ks * 32 + quad * 8];
        accS[cb] = __builtin_amdgcn_mfma_f32_16x16x32_bf16(aq[ks], bk, accS[cb], 0, 0, 0);
      }
    // positional band T[16][80]; clamp folded into band-row index
    int tb = ib - j0 + 512 - 63;
    f32x4 accT[5] = {};
    #pragma unroll
    for (int ks = 0; ks < 2; ++ks)
      #pragma unroll
      for (int ub = 0; ub < 5; ++ub) {
        int trow = tb + ub * 16 + q15;
        trow = trow < 0 ? 0 : (trow > 1024 ? 1024 : trow);
        bf16x8 br = *(const bf16x8*)&rel[(size_t)trow * 64 + ks * 32 + quad * 8];
        accT[ub] = __builtin_amdgcn_mfma_f32_16x16x32_bf16(aq[ks], br, accT[ub], 0, 0, 0);
      }
    #pragma unroll
    for (int ub = 0; ub < 5; ++ub)
      #pragma unroll
      for (int r = 0; r < 4; ++r)
        T_lds[w][quad * 4 + r][ub * 16 + q15] = accT[ub][r];
    __syncthreads();  // T + vt visible

    // assemble S, online softmax (row lives across the 16 lanes of a quad-group)
    float s[4][4];
    #pragma unroll
    for (int cb = 0; cb < 4; ++cb)
      #pragma unroll
      for (int r = 0; r < 4; ++r) {
        int dl = quad * 4 + r, dj = cb * 16 + q15;
        s[cb][r] = (accS[cb][r] + T_lds[w][dl][63 + dl - dj]) * 0.125f;
      }
    #pragma unroll
    for (int r = 0; r < 4; ++r) {
      float mx = fmaxf(fmaxf(s[0][r], s[1][r]), fmaxf(s[2][r], s[3][r]));
      #pragma unroll
      for (int off = 1; off < 16; off <<= 1)
        mx = fmaxf(mx, __shfl_xor(mx, off, 64));
      float mnew = fmaxf(m_i[r], mx);
      float alpha = exp2f(fmaxf((m_i[r] - mnew) * 1.44269504f, -126.f));
      m_i[r] = mnew;
      float pr[4], sum = 0.f;
      #pragma unroll
      for (int cb = 0; cb < 4; ++cb) {
        pr[cb] = exp2f(fmaxf((s[cb][r] - mnew) * 1.44269504f, -126.f));
        sum += pr[cb];
      }
      #pragma unroll
      for (int off = 1; off < 16; off <<= 1)
        sum += __shfl_xor(sum, off, 64);
      l_i[r] = l_i[r] * alpha + sum;
      #pragma unroll
      for (int db = 0; db < 4; ++db) o[db][r] *= alpha;
      #pragma unroll
      for (int cb = 0; cb < 4; ++cb)
        P_lds[w][quad * 4 + r][cb * 16 + q15] = f2bf(pr[cb]);
    }
    __syncthreads();  // P visible

    // O += P @ V   (P from LDS in A-layout, V^T rows give B-layout)
    #pragma unroll
    for (int ks = 0; ks < 2; ++ks) {
      bf16x8 ap = *(const bf16x8*)&P_lds[w][q15][ks * 32 + quad * 8];
      #pragma unroll
      for (int db = 0; db < 4; ++db) {
        bf16x8 bv = *(const bf16x8*)&vt[db * 16 + q15][ks * 32 + quad * 8];
        o[db] = __builtin_amdgcn_mfma_f32_16x16x32_bf16(ap, bv, o[db], 0, 0, 0);
      }
    }
  }

  // epilogue: ao[b*1024 + i][h*64 + d] = O / l
  int b = bh >> 4, h = bh & 15;
  #pragma unroll
  for (int db = 0; db < 4; ++db)
    #pragma unroll
    for (int r = 0; r < 4; ++r) {
      int row = ib + quad * 4 + r;
      float val = o[db][r] / l_i[r];
      ao[((size_t)(b * 1024 + row)) * 1024 + h * 64 + db * 16 + q15] = f2bf(val);
    }
}

// ---------------------------------------------------------------------------
extern "C" void kernel_launch(void* const* d_in, const int* in_sizes, int n_in,
                              void* d_out, int out_size, void* d_ws, size_t ws_size,
                              hipStream_t stream) {
  (void)in_sizes; (void)n_in; (void)out_size; (void)ws_size;
  const void* x   = d_in[0];  // [2,1024,1024]
  const void* Wq  = d_in[1];  // [1024,1024]
  const void* Wkv = d_in[2];  // [1024,2048]
  const void* Wo  = d_in[3];  // [1024,1024]
  const void* bo  = d_in[4];  // [1024]
  const void* rel = d_in[5];  // [1025,64]
  float* out = (float*)d_out;  // [2,1024,1024] float32 (reference output dtype)

  unsigned short* ws = (unsigned short*)d_ws;
  unsigned short* xb    = ws;                     // 2,097,152 el (ao aliases)
  unsigned short* WqkvT = xb    + 2097152;        // 3,145,728 el
  unsigned short* WoT   = WqkvT + 3145728;        // 1,048,576 el
  unsigned short* relb  = WoT   + 1048576;        // 65,600 (reserve 65,664)
  unsigned short* bob   = relb  + 65664;          // 1024
  int*            flagp = (int*)(bob + 1024);     // reserve 64 el
  unsigned short* q_ws  = bob   + 1024 + 64;      // 2,097,152 el each
  unsigned short* k_ws  = q_ws  + 2097152;
  unsigned short* v_ws  = k_ws  + 2097152;
  unsigned short* ao    = xb;   // alias: xb dead after gemm1

  detect_dtype_k<<<1, 256, 0, stream>>>((const unsigned short*)x, flagp);

  cvt_k<<<2048, 256, 0, stream>>>(x,   xb,   2097152, flagp);
  cvt_k<<<64,   256, 0, stream>>>(rel, relb, 65600,   flagp);
  cvt_k<<<4,    256, 0, stream>>>(bo,  bob,  1024,    flagp);

  dim3 tb(32, 8);
  transpose_cvt_k<<<dim3(32, 32), tb, 0, stream>>>(Wq,  WqkvT,           1024, 1024, flagp);
  transpose_cvt_k<<<dim3(64, 32), tb, 0, stream>>>(Wkv, WqkvT + 1048576, 1024, 2048, flagp);
  transpose_cvt_k<<<dim3(32, 32), tb, 0, stream>>>(Wo,  WoT,             1024, 1024, flagp);

  // x @ [Wq | Wk | Wv]  ->  q/k/v in [b,h,n,d]
  gemm_bt<<<dim3(24, 16), 256, 0, stream>>>(xb, WqkvT, 2048, 3072, 1024, 1,
                                            nullptr, q_ws, k_ws, v_ws, nullptr);
  flash_attn<<<dim3(16, 32), 256, 0, stream>>>(q_ws, k_ws, v_ws, relb, ao);
  // ao @ Wo + bo -> out (f32)
  gemm_bt<<<dim3(8, 16), 256, 0, stream>>>(ao, WoT, 2048, 1024, 1024, 2,
                                           bob, nullptr, nullptr, nullptr, out);
}